// Round 7
// baseline (5938.065 us; speedup 1.0000x reference)
//
#include <hip/hip_runtime.h>

#define B_    64
#define L1C   4093
#define L2C   4086
#define L3C   4071
#define TDEC  60

static __device__ __forceinline__ float sigf(float x){ return 1.f/(1.f + __expf(-x)); }
static __device__ __forceinline__ unsigned f2bf(float f){
  unsigned u = __float_as_uint(f);
  u = u + 0x7fffu + ((u >> 16) & 1u);   // RNE to bf16
  return (u >> 16);
}
static __device__ __forceinline__ float bfl(unsigned u){ return __uint_as_float(u<<16); }
static __device__ __forceinline__ float bfh(unsigned u){ return __uint_as_float(u & 0xffff0000u); }

// ---------------- conv stack ----------------
template<int CIN,int COUT,int KW,bool BF16OUT>
__global__ __launch_bounds__(256) void k_conv(
    const float* __restrict__ in, const float* __restrict__ w,
    const float* __restrict__ bias, void* __restrict__ outp,
    int Lin_, int Lout_)
{
  int g = blockIdx.x*256 + threadIdx.x;
  int bi = g / Lout_;
  int l  = g - bi*Lout_;
  if (bi >= B_) return;
  float acc[COUT];
#pragma unroll
  for (int o=0;o<COUT;o++) acc[o] = bias[o];
  const float* ip = in + ((size_t)bi*Lin_ + l)*CIN;
  for (int k=0;k<KW;k++){
#pragma unroll
    for (int i4=0;i4<CIN/4;i4++){
      float4 xv = *(const float4*)(ip + k*CIN + i4*4);
#pragma unroll
      for (int c=0;c<4;c++){
        float xs = (&xv.x)[c];
        int i = i4*4+c;
#pragma unroll
        for (int o=0;o<COUT;o++)
          acc[o] = fmaf(xs, w[(o*CIN + i)*KW + k], acc[o]);
      }
    }
  }
  if constexpr (BF16OUT){
    unsigned* op = (unsigned*)outp + ((size_t)bi*Lout_ + l)*(COUT/2);
#pragma unroll
    for (int o2=0;o2<COUT/2;o2++){
      unsigned lo = f2bf(fmaxf(acc[2*o2],0.f));
      unsigned hi = f2bf(fmaxf(acc[2*o2+1],0.f));
      op[o2] = lo | (hi<<16);
    }
  } else {
    float* op = (float*)outp + ((size_t)bi*Lout_ + l)*COUT;
#pragma unroll
    for (int o=0;o<COUT;o++) op[o] = fmaxf(acc[o],0.f);
  }
}

// ---------------- pack weights: [2][1024][K] fp32 -> [2][K/8][1024] bf16x8 ----------------
__global__ __launch_bounds__(256) void k_packw2(
    const float* __restrict__ w, uint4* __restrict__ wT, int K)
{
  int gid = blockIdx.x*256 + threadIdx.x;
  int per = (K/8)*1024;
  int d = gid / per, rem = gid - d*per;
  int j8 = rem >> 10, row = rem & 1023;
  const float* src = w + ((size_t)d*1024 + row)*K + j8*8;
  float4 a = *(const float4*)src;
  float4 b = *(const float4*)(src+4);
  uint4 o;
  o.x = f2bf(a.x) | (f2bf(a.y)<<16);
  o.y = f2bf(a.z) | (f2bf(a.w)<<16);
  o.z = f2bf(b.x) | (f2bf(b.y)<<16);
  o.w = f2bf(b.z) | (f2bf(b.w)<<16);
  wT[gid] = o;
}

#define GATE8(gv, wv, hh0, hh1) \
  gv = fmaf(bfl(wv.x), hh0.x, gv); gv = fmaf(bfh(wv.x), hh0.y, gv); \
  gv = fmaf(bfl(wv.y), hh0.z, gv); gv = fmaf(bfh(wv.y), hh0.w, gv); \
  gv = fmaf(bfl(wv.z), hh1.x, gv); gv = fmaf(bfh(wv.z), hh1.y, gv); \
  gv = fmaf(bfl(wv.w), hh1.z, gv); gv = fmaf(bfh(wv.w), hh1.w, gv);

// ---------------- dec1: block = b (BOTH dirs), flash single-pass attention ----------------
// 64 blocks x 1024 thr. enc row read once per step, used for both dirs' scores+ctx.
// Per-XCD L2 footprint: 8 enc slices (2.08 MB) + whh both dirs (2 MB) -> resident.
__global__ __launch_bounds__(1024, 4) void k_dec1d(
    const unsigned* __restrict__ enc,      // [B][L3C][16] uints (bf16 pairs, 32 ch)
    const float* __restrict__ attn_w,      // [256][32]
    const uint4* __restrict__ wihT,        // [2][4][1024] bf16x8 (K=32)
    const uint4* __restrict__ whhT,        // [2][32][1024] bf16x8 (K=256)
    const float* __restrict__ bih, const float* __restrict__ bhh,
    float* __restrict__ d2in)              // [B][60][512]
{
  int b = blockIdx.x, tid = threadIdx.x;
  int p = tid & 1, rb = tid >> 1;          // pair covers rows rb+512k, k=0..7
  __shared__ __align__(16) float hls[2][256];
  __shared__ __align__(16) float vl[2][32];
  __shared__ float red[1024];
  __shared__ float scr[2][16][32];
  __shared__ __align__(16) float ctx[2][32];
  __shared__ float gls[2][1024];

  if (tid < 512) ((float*)hls)[tid] = 0.f;
  float creg = 0.f;                        // for tid<512: (d=tid>>8, row=tid&255)
  float bsum0 = bih[tid]        + bhh[tid];
  float bsum1 = bih[1024 + tid] + bhh[1024 + tid];
  const uint4* encb = (const uint4*)(enc + (size_t)b*L3C*16);   // row l = 4 uint4
  __syncthreads();

  for (int t=0; t<TDEC; t++){
    // -- phase 1: v[d][c] = sum_u h[d][u]*attn_w[u][c] --
    {
      int d = tid >> 9, rem = tid & 511;
      int c = rem & 31, part = rem >> 5;          // 16 parts x 16 u
      const float* wp = attn_w + (size_t)(part*16)*32 + c;
      const float* hp = &hls[d][part*16];
      float s = 0.f;
#pragma unroll
      for (int k=0;k<16;k++) s = fmaf(hp[k], wp[k*32], s);
      red[tid] = s;
    }
    __syncthreads();                              // A
    if (tid < 64){
      int d = tid>>5, c = tid&31;
      float v = 0.f;
#pragma unroll
      for (int q=0;q<16;q++) v += red[d*512 + q*32 + c];
      vl[d][c] = v;
    }
    __syncthreads();                              // B

    // -- phase 2: flash single pass, both dirs --
    float vreg0[16], vreg1[16];
    *(float4*)&vreg0[0]  = *(const float4*)&vl[0][p*16];
    *(float4*)&vreg0[4]  = *(const float4*)&vl[0][p*16+4];
    *(float4*)&vreg0[8]  = *(const float4*)&vl[0][p*16+8];
    *(float4*)&vreg0[12] = *(const float4*)&vl[0][p*16+12];
    *(float4*)&vreg1[0]  = *(const float4*)&vl[1][p*16];
    *(float4*)&vreg1[4]  = *(const float4*)&vl[1][p*16+4];
    *(float4*)&vreg1[8]  = *(const float4*)&vl[1][p*16+8];
    *(float4*)&vreg1[12] = *(const float4*)&vl[1][p*16+12];
    float m0 = -3.0e38f, ss0 = 0.f, m1 = -3.0e38f, ss1 = 0.f;
    float acc0[16], acc1[16];
#pragma unroll
    for (int j=0;j<16;j++){ acc0[j]=0.f; acc1[j]=0.f; }
#pragma unroll
    for (int k=0;k<8;k++){
      int l = rb + 512*k;
      bool valid = (l < L3C);
      uint4 u0 = valid ? encb[(size_t)l*4 + 2*p]     : make_uint4(0,0,0,0);
      uint4 u1 = valid ? encb[(size_t)l*4 + 2*p + 1] : make_uint4(0,0,0,0);
      float r[16];
      r[0]=bfl(u0.x); r[1]=bfh(u0.x); r[2]=bfl(u0.y); r[3]=bfh(u0.y);
      r[4]=bfl(u0.z); r[5]=bfh(u0.z); r[6]=bfl(u0.w); r[7]=bfh(u0.w);
      r[8]=bfl(u1.x); r[9]=bfh(u1.x); r[10]=bfl(u1.y); r[11]=bfh(u1.y);
      r[12]=bfl(u1.z); r[13]=bfh(u1.z); r[14]=bfl(u1.w); r[15]=bfh(u1.w);
      float s0 = 0.f, s1 = 0.f;
#pragma unroll
      for (int j=0;j<16;j++){ s0 = fmaf(r[j], vreg0[j], s0); s1 = fmaf(r[j], vreg1[j], s1); }
      s0 += __shfl_xor(s0, 1);
      s1 += __shfl_xor(s1, 1);
      if (!valid){ s0 = -3.0e38f; s1 = -3.0e38f; }
      {
        float mn = fmaxf(m0, s0);
        float al = __expf(m0 - mn);
        float e  = __expf(s0 - mn);
        ss0 = ss0*al + ((p==0) ? e : 0.f);
#pragma unroll
        for (int j=0;j<16;j++) acc0[j] = fmaf(e, r[j], acc0[j]*al);
        m0 = mn;
      }
      {
        float mn = fmaxf(m1, s1);
        float al = __expf(m1 - mn);
        float e  = __expf(s1 - mn);
        ss1 = ss1*al + ((p==0) ? e : 0.f);
#pragma unroll
        for (int j=0;j<16;j++) acc1[j] = fmaf(e, r[j], acc1[j]*al);
        m1 = mn;
      }
    }
    // block max per dir
    float bm0 = m0, bm1 = m1;
#pragma unroll
    for (int off=32; off; off>>=1){ bm0 = fmaxf(bm0, __shfl_xor(bm0, off)); bm1 = fmaxf(bm1, __shfl_xor(bm1, off)); }
    int wid = tid >> 6;
    if ((tid&63)==0){ red[wid] = bm0; red[16+wid] = bm1; }
    __syncthreads();                              // C
    float gm0 = red[0], gm1 = red[16];
#pragma unroll
    for (int i=1;i<16;i++){ gm0 = fmaxf(gm0, red[i]); gm1 = fmaxf(gm1, red[16+i]); }
    float sc0 = __expf(m0 - gm0), sc1 = __expf(m1 - gm1);
    ss0 *= sc0; ss1 *= sc1;
#pragma unroll
    for (int j=0;j<16;j++){ acc0[j] *= sc0; acc1[j] *= sc1; }
#pragma unroll
    for (int off=32; off; off>>=1){ ss0 += __shfl_xor(ss0, off); ss1 += __shfl_xor(ss1, off); }
    if ((tid&63)==0){ red[32+wid] = ss0; red[48+wid] = ss1; }
#pragma unroll
    for (int off=2; off<=32; off<<=1){
#pragma unroll
      for (int j=0;j<16;j++){ acc0[j] += __shfl_xor(acc0[j], off); acc1[j] += __shfl_xor(acc1[j], off); }
    }
    if ((tid&63) < 2){
#pragma unroll
      for (int j=0;j<16;j++){ scr[0][wid][p*16+j] = acc0[j]; scr[1][wid][p*16+j] = acc1[j]; }
    }
    __syncthreads();                              // D
    if (tid < 64){
      int d = tid>>5, c = tid&31;
      float S = 0.f, s2 = 0.f;
#pragma unroll
      for (int w=0;w<16;w++){ S += red[32 + d*16 + w]; s2 += scr[d][w][c]; }
      ctx[d][c] = s2 / S;
    }
    __syncthreads();                              // E

    // -- phase 3: gates, both dirs (gate row = tid per dir) --
    float g0 = bsum0, g1 = bsum1;
#pragma unroll
    for (int c8=0;c8<4;c8++){
      uint4 wv0 = wihT[c8*1024 + tid];
      uint4 wv1 = wihT[4096 + c8*1024 + tid];
      float4 x00 = *(const float4*)&ctx[0][c8*8];
      float4 x01 = *(const float4*)&ctx[0][c8*8+4];
      float4 x10 = *(const float4*)&ctx[1][c8*8];
      float4 x11 = *(const float4*)&ctx[1][c8*8+4];
      GATE8(g0, wv0, x00, x01)
      GATE8(g1, wv1, x10, x11)
    }
#pragma unroll 4
    for (int j8=0;j8<32;j8++){
      uint4 wv0 = whhT[j8*1024 + tid];
      uint4 wv1 = whhT[32768 + j8*1024 + tid];
      float4 h00 = *(const float4*)&hls[0][j8*8];
      float4 h01 = *(const float4*)&hls[0][j8*8+4];
      float4 h10 = *(const float4*)&hls[1][j8*8];
      float4 h11 = *(const float4*)&hls[1][j8*8+4];
      GATE8(g0, wv0, h00, h01)
      GATE8(g1, wv1, h10, h11)
    }
    gls[0][tid] = g0;
    gls[1][tid] = g1;
    __syncthreads();                              // F
    if (tid < 512){
      int d = tid >> 8, r = tid & 255;
      float ii = sigf(gls[d][r]);
      float ff = sigf(gls[d][256+r]);
      float gg = tanhf(gls[d][512+r]);
      float oo = sigf(gls[d][768+r]);
      creg = fmaf(ff, creg, ii*gg);
      float hn = oo * tanhf(creg);
      hls[d][r] = hn;
      int tout = d ? (59 - t) : t;
      d2in[((size_t)b*60 + tout)*512 + d*256 + r] = hn;
    }
    __syncthreads();                              // G
  }
}

// ---------------- generic fp32 GEMM ----------------
__global__ __launch_bounds__(256) void k_gemm(
    const float* __restrict__ A, const float* __restrict__ W,
    float* __restrict__ C, const float* __restrict__ b1, const float* __restrict__ b2,
    int K, int ldc, size_t sW, size_t sC, int sB)
{
  int m0 = blockIdx.x * 128, n0 = blockIdx.y * 128, z = blockIdx.z;
  const float* Wz = W + (size_t)z*sW;
  float* Cz = C + (size_t)z*sC;
  const float* b1z = b1 + (size_t)z*sB;
  const float* b2z = b2 ? (b2 + (size_t)z*sB) : nullptr;
  __shared__ __align__(16) float As[16][132];
  __shared__ __align__(16) float Bs[16][132];
  int tid = threadIdx.x;
  int tx = tid & 15, ty = tid >> 4;
  int r = tid >> 2, c4 = tid & 3;
  float acc[8][8] = {};
  for (int k0=0; k0<K; k0+=16){
#pragma unroll
    for (int h=0; h<2; h++){
      int rr = r + h*64;
      float4 av = *(const float4*)(A  + (size_t)(m0+rr)*K + k0 + c4*4);
      float4 bv = *(const float4*)(Wz + (size_t)(n0+rr)*K + k0 + c4*4);
      As[c4*4+0][rr]=av.x; As[c4*4+1][rr]=av.y; As[c4*4+2][rr]=av.z; As[c4*4+3][rr]=av.w;
      Bs[c4*4+0][rr]=bv.x; Bs[c4*4+1][rr]=bv.y; Bs[c4*4+2][rr]=bv.z; Bs[c4*4+3][rr]=bv.w;
    }
    __syncthreads();
#pragma unroll
    for (int kk=0; kk<16; kk++){
      float a[8], bb[8];
      *(float4*)&a[0]  = *(const float4*)&As[kk][ty*8];
      *(float4*)&a[4]  = *(const float4*)&As[kk][ty*8+4];
      *(float4*)&bb[0] = *(const float4*)&Bs[kk][tx*8];
      *(float4*)&bb[4] = *(const float4*)&Bs[kk][tx*8+4];
#pragma unroll
      for (int i=0;i<8;i++)
#pragma unroll
        for (int j=0;j<8;j++)
          acc[i][j] = fmaf(a[i], bb[j], acc[i][j]);
    }
    __syncthreads();
  }
  float bb1[8];
#pragma unroll
  for (int j=0;j<8;j++){
    int n = n0 + tx*8 + j;
    bb1[j] = b1z[n] + (b2z ? b2z[n] : 0.f);
  }
#pragma unroll
  for (int i=0;i<8;i++){
    int m = m0 + ty*8 + i;
    float o[8];
#pragma unroll
    for (int j=0;j<8;j++) o[j] = acc[i][j] + bb1[j];
    *(float4*)(Cz + (size_t)m*ldc + n0 + tx*8)     = *(const float4*)&o[0];
    *(float4*)(Cz + (size_t)m*ldc + n0 + tx*8 + 4) = *(const float4*)&o[4];
  }
}

// ---------------- dec2: recurrent, block = (dir, batch), 16 waves ----------------
__global__ __launch_bounds__(1024) void k_rec2(
    const float* __restrict__ xg,   // [2][64][60][1024]
    const uint4* __restrict__ wT,   // [2][32][1024] bf16x8
    float* __restrict__ out)        // [64][60][512]
{
  int b = blockIdx.x, d = blockIdx.y, tid = threadIdx.x;
  __shared__ __align__(16) float hls[256];
  __shared__ float gls[1024];
  float c = 0.f;
  if (tid < 256) hls[tid] = 0.f;
  __syncthreads();
  const uint4* wp = wT + (size_t)d*32*1024;
  const float* xp = xg + (((size_t)d*64 + b)*60)*1024;
  for (int step=0; step<TDEC; step++){
    int t = d ? (TDEC-1-step) : step;
    float g = xp[(size_t)t*1024 + tid];
#pragma unroll 4
    for (int j8=0;j8<32;j8++){
      uint4 wv = wp[j8*1024 + tid];
      float4 h0 = *(const float4*)&hls[j8*8];
      float4 h1 = *(const float4*)&hls[j8*8+4];
      GATE8(g, wv, h0, h1)
    }
    gls[tid] = g;
    __syncthreads();
    if (tid < 256){
      float ii = sigf(gls[tid]);
      float ff = sigf(gls[256+tid]);
      float gg = tanhf(gls[512+tid]);
      float oo = sigf(gls[768+tid]);
      c = fmaf(ff, c, ii*gg);
      float hn = oo * tanhf(c);
      hls[tid] = hn;
      out[((size_t)b*60 + t)*512 + d*256 + tid] = hn;
    }
    __syncthreads();
  }
}

extern "C" void kernel_launch(void* const* d_in, const int* in_sizes, int n_in,
                              void* d_out, int out_size, void* d_ws, size_t ws_size,
                              hipStream_t stream) {
  const float* x      = (const float*)d_in[0];
  const float* cw1    = (const float*)d_in[1];
  const float* cb1    = (const float*)d_in[2];
  const float* cw2    = (const float*)d_in[3];
  const float* cb2    = (const float*)d_in[4];
  const float* cw3    = (const float*)d_in[5];
  const float* cb3    = (const float*)d_in[6];
  const float* attn_w = (const float*)d_in[7];
  // d_in[8] attn_b: constant over softmax axis -> drops out analytically
  const float* d1_wih = (const float*)d_in[9];
  const float* d1_whh = (const float*)d_in[10];
  const float* d1_bih = (const float*)d_in[11];
  const float* d1_bhh = (const float*)d_in[12];
  const float* w2_ih0 = (const float*)d_in[13];
  const float* w2_hh0 = (const float*)d_in[14];
  const float* b2_ih0 = (const float*)d_in[15];
  const float* b2_hh0 = (const float*)d_in[16];
  const float* w2_ih1 = (const float*)d_in[17];
  const float* w2_hh1 = (const float*)d_in[18];
  const float* b2_ih1 = (const float*)d_in[19];
  const float* b2_hh1 = (const float*)d_in[20];
  const float* out_w  = (const float*)d_in[21];
  const float* out_b  = (const float*)d_in[22];

  char* ws = (char*)d_ws;
  size_t off = 0;
  unsigned* enc = (unsigned*)(ws + off); off += 16675840;          // bf16 enc, padded
  size_t off_h1 = off;
  float* h1buf = (float*)(ws + off); off += 8382464;               // (B,4093,8)
  float* h2buf = (float*)(ws + off); off += 16736256;              // (B,4086,16)
  float* d2in  = (float*)(ws + off_h1);                            // reuse: (B,60,512)
  float* l0    = (float*)(ws + off_h1 + 7864320);
  float* l1    = (float*)(ws + off_h1 + 15728640);
  uint4* wT    = (uint4*)(ws + off_h1 + 23592960);                 // 1MB dec2 pack (dead tail)
  float* xg    = (float*)(ws + off); off += 31457280;              // [2][B][60][1024]
  // dec1 packs live INSIDE the xg region (xg written only after dec1 completes)
  uint4* d1whhT = (uint4*)xg;                                      // 1 MB
  uint4* d1wihT = (uint4*)((char*)xg + 1048576);                   // +128 KB
  (void)ws_size; (void)in_sizes; (void)n_in; (void)out_size;

  // dec1 weight packs (before dec1; clobbered later by xg — fine)
  k_packw2<<<256,256,0,stream>>>(d1_whh, d1whhT, 256);
  k_packw2<<<32, 256,0,stream>>>(d1_wih, d1wihT, 32);

  int g1 = (B_*L1C + 255)/256;
  k_conv<64,8,4,false><<<g1,256,0,stream>>>(x, cw1, cb1, h1buf, 4096, L1C);
  int g2 = (B_*L2C + 255)/256;
  k_conv<8,16,8,false><<<g2,256,0,stream>>>(h1buf, cw2, cb2, h2buf, L1C, L2C);
  int g3 = (B_*L3C + 255)/256;
  k_conv<16,32,16,true><<<g3,256,0,stream>>>(h2buf, cw3, cb3, enc, L2C, L3C);

  // dec1: one block per b, both dirs fused (enc read once/step; L2-resident per XCD)
  k_dec1d<<<dim3(64),1024,0,stream>>>(enc, attn_w, d1wihT, d1whhT,
                                      d1_bih, d1_bhh, d2in);

  // dec2 layer 0
  k_packw2<<<256,256,0,stream>>>(w2_hh0, wT, 256);
  k_gemm<<<dim3(30,8,2),256,0,stream>>>(d2in, w2_ih0, xg, b2_ih0, b2_hh0,
                                        512, 1024, (size_t)1024*512, (size_t)3840*1024, 1024);
  k_rec2<<<dim3(64,2),1024,0,stream>>>(xg, wT, l0);
  // dec2 layer 1
  k_packw2<<<256,256,0,stream>>>(w2_hh1, wT, 256);
  k_gemm<<<dim3(30,8,2),256,0,stream>>>(l0, w2_ih1, xg, b2_ih1, b2_hh1,
                                        512, 1024, (size_t)1024*512, (size_t)3840*1024, 1024);
  k_rec2<<<dim3(64,2),1024,0,stream>>>(xg, wT, l1);
  // output projection
  k_gemm<<<dim3(30,1,1),256,0,stream>>>(l1, out_w, (float*)d_out, out_b, nullptr,
                                        512, 128, 0, 0, 0);
}

// Round 8
// 4536.655 us; speedup vs baseline: 1.3089x; 1.3089x over previous
//
#include <hip/hip_runtime.h>

#define B_    64
#define L1C   4093
#define L2C   4086
#define L3C   4071
#define TDEC  60

static __device__ __forceinline__ float sigf(float x){ return 1.f/(1.f + __expf(-x)); }
static __device__ __forceinline__ unsigned f2bf(float f){
  unsigned u = __float_as_uint(f);
  u = u + 0x7fffu + ((u >> 16) & 1u);   // RNE to bf16
  return (u >> 16);
}
static __device__ __forceinline__ float bfl(unsigned u){ return __uint_as_float(u<<16); }
static __device__ __forceinline__ float bfh(unsigned u){ return __uint_as_float(u & 0xffff0000u); }

// ---------------- conv stack ----------------
template<int CIN,int COUT,int KW,bool BF16OUT>
__global__ __launch_bounds__(256) void k_conv(
    const float* __restrict__ in, const float* __restrict__ w,
    const float* __restrict__ bias, void* __restrict__ outp,
    int Lin_, int Lout_)
{
  int g = blockIdx.x*256 + threadIdx.x;
  int bi = g / Lout_;
  int l  = g - bi*Lout_;
  if (bi >= B_) return;
  float acc[COUT];
#pragma unroll
  for (int o=0;o<COUT;o++) acc[o] = bias[o];
  const float* ip = in + ((size_t)bi*Lin_ + l)*CIN;
  for (int k=0;k<KW;k++){
#pragma unroll
    for (int i4=0;i4<CIN/4;i4++){
      float4 xv = *(const float4*)(ip + k*CIN + i4*4);
#pragma unroll
      for (int c=0;c<4;c++){
        float xs = (&xv.x)[c];
        int i = i4*4+c;
#pragma unroll
        for (int o=0;o<COUT;o++)
          acc[o] = fmaf(xs, w[(o*CIN + i)*KW + k], acc[o]);
      }
    }
  }
  if constexpr (BF16OUT){
    unsigned* op = (unsigned*)outp + ((size_t)bi*Lout_ + l)*(COUT/2);
#pragma unroll
    for (int o2=0;o2<COUT/2;o2++){
      unsigned lo = f2bf(fmaxf(acc[2*o2],0.f));
      unsigned hi = f2bf(fmaxf(acc[2*o2+1],0.f));
      op[o2] = lo | (hi<<16);
    }
  } else {
    float* op = (float*)outp + ((size_t)bi*Lout_ + l)*COUT;
#pragma unroll
    for (int o=0;o<COUT;o++) op[o] = fmaxf(acc[o],0.f);
  }
}

// ---------------- pack weights: [2][1024][K] fp32 -> [2][K/8][1024] bf16x8 ----------------
__global__ __launch_bounds__(256) void k_packw2(
    const float* __restrict__ w, uint4* __restrict__ wT, int K)
{
  int gid = blockIdx.x*256 + threadIdx.x;
  int per = (K/8)*1024;
  int d = gid / per, rem = gid - d*per;
  int j8 = rem >> 10, row = rem & 1023;
  const float* src = w + ((size_t)d*1024 + row)*K + j8*8;
  float4 a = *(const float4*)src;
  float4 b = *(const float4*)(src+4);
  uint4 o;
  o.x = f2bf(a.x) | (f2bf(a.y)<<16);
  o.y = f2bf(a.z) | (f2bf(a.w)<<16);
  o.z = f2bf(b.x) | (f2bf(b.y)<<16);
  o.w = f2bf(b.z) | (f2bf(b.w)<<16);
  wT[gid] = o;
}

#define GATE8(gv, wv, hh0, hh1) \
  gv = fmaf(bfl(wv.x), hh0.x, gv); gv = fmaf(bfh(wv.x), hh0.y, gv); \
  gv = fmaf(bfl(wv.y), hh0.z, gv); gv = fmaf(bfh(wv.y), hh0.w, gv); \
  gv = fmaf(bfl(wv.z), hh1.x, gv); gv = fmaf(bfh(wv.z), hh1.y, gv); \
  gv = fmaf(bfl(wv.w), hh1.z, gv); gv = fmaf(bfh(wv.w), hh1.w, gv);

// ---------------- dec1: block=(b, L-half q); enc half resident in LDS (128 KB) ----------------
// 128 blocks x 1024 thr, 1 block/CU (146 KB LDS). Twin blocks (b,0)/(b,1) exchange
// softmax partials + h via device-scope atomics; co-residency: 128 blocks <= 256 CUs.
__global__ __launch_bounds__(1024, 1) void k_dec1e(
    const unsigned* __restrict__ enc,      // [B][L3C][16] uints (bf16 pairs, 32 ch)
    const float* __restrict__ attn_w,      // [256][32]
    const uint4* __restrict__ wihT,        // [2][4][1024] bf16x8 (K=32)
    const uint4* __restrict__ whhT,        // [2][32][1024] bf16x8 (K=256)
    const float* __restrict__ bih, const float* __restrict__ bhh,
    float* __restrict__ d2in,              // [B][60][512]
    float* __restrict__ pbuf,              // [B][2 half][2 dir][34]
    float* __restrict__ hbuf,              // [B][2 dir][256]
    unsigned* __restrict__ flagA,          // [B][2]
    unsigned* __restrict__ flagB)          // [B][2]
{
  int blk = blockIdx.x;
  int b = blk & 63, q = blk >> 6;
  int tid = threadIdx.x;
  int p = tid & 1, rb = tid >> 1;          // parity-pair covers rows rb+512k, k=0..3
  int base  = q ? 2048 : 0;
  int nrows = q ? (L3C - 2048) : 2048;     // 2023 : 2048

  __shared__ __align__(16) uint4 encL[8192];     // 128 KB: [row][4] (row = 32 bf16)
  __shared__ __align__(16) float hls[2][256];
  __shared__ __align__(16) float vl[2][32];
  __shared__ float red[1024];
  __shared__ float wacc[2][16][32];
  __shared__ float wms[16][2];
  __shared__ float wssL[16][2];
  __shared__ __align__(16) float ctx[2][32];
  __shared__ float gls[1024];

  { // stage enc half once (coalesced uint4)
    const uint4* src = (const uint4*)(enc + (size_t)b*L3C*16) + (size_t)base*4;
    int n4 = nrows*4;
    for (int i = tid; i < 8192; i += 1024)
      encL[i] = (i < n4) ? src[i] : make_uint4(0,0,0,0);
  }
  if (tid < 512) ((float*)hls)[tid] = 0.f;
  float creg = 0.f;                        // c-state for dir q, row tid (tid<256)
  float bsum = bih[(size_t)q*1024 + tid] + bhh[(size_t)q*1024 + tid];
  const uint4* whp = whhT + (size_t)q*32768;
  __syncthreads();

  for (int t=0; t<TDEC; t++){
    // -- phase 1: v[d][c] = sum_u h[d][u]*attn_w[u][c] --
    {
      int d = tid >> 9, rem = tid & 511;
      int c = rem & 31, part = rem >> 5;   // 16 parts x 16 u
      const float* wp = attn_w + (size_t)(part*16)*32 + c;
      const float* hp = &hls[d][part*16];
      float s = 0.f;
#pragma unroll
      for (int k=0;k<16;k++) s = fmaf(hp[k], wp[k*32], s);
      red[tid] = s;
    }
    __syncthreads();
    if (tid < 64){
      int d = tid>>5, c = tid&31;
      float v = 0.f;
#pragma unroll
      for (int u=0;u<16;u++) v += red[d*512 + u*32 + c];
      vl[d][c] = v;
    }
    __syncthreads();

    // -- phase 2: flash over LDS rows, both dirs --
    float vreg0[16], vreg1[16];
#pragma unroll
    for (int j=0;j<16;j++){ vreg0[j] = vl[0][p*16+j]; vreg1[j] = vl[1][p*16+j]; }
    float m0 = -3.0e38f, ss0 = 0.f, m1 = -3.0e38f, ss1 = 0.f;
    float acc0[16], acc1[16];
#pragma unroll
    for (int j=0;j<16;j++){ acc0[j]=0.f; acc1[j]=0.f; }
#pragma unroll
    for (int k=0;k<4;k++){
      int l = rb + 512*k;
      bool valid = (l < nrows);
      uint4 u0 = encL[l*4 + 2*p];
      uint4 u1 = encL[l*4 + 2*p + 1];
      float r[16];
      r[0]=bfl(u0.x); r[1]=bfh(u0.x); r[2]=bfl(u0.y); r[3]=bfh(u0.y);
      r[4]=bfl(u0.z); r[5]=bfh(u0.z); r[6]=bfl(u0.w); r[7]=bfh(u0.w);
      r[8]=bfl(u1.x); r[9]=bfh(u1.x); r[10]=bfl(u1.y); r[11]=bfh(u1.y);
      r[12]=bfl(u1.z); r[13]=bfh(u1.z); r[14]=bfl(u1.w); r[15]=bfh(u1.w);
      float s0 = 0.f, s1 = 0.f;
#pragma unroll
      for (int j=0;j<16;j++){ s0 = fmaf(r[j], vreg0[j], s0); s1 = fmaf(r[j], vreg1[j], s1); }
      s0 += __shfl_xor(s0, 1);
      s1 += __shfl_xor(s1, 1);
      if (!valid){ s0 = -3.0e38f; s1 = -3.0e38f; }
      {
        float mn = fmaxf(m0, s0);
        float al = __expf(m0 - mn);
        float e  = __expf(s0 - mn);
        ss0 = ss0*al + ((p==0) ? e : 0.f);
#pragma unroll
        for (int j=0;j<16;j++) acc0[j] = fmaf(e, r[j], acc0[j]*al);
        m0 = mn;
      }
      {
        float mn = fmaxf(m1, s1);
        float al = __expf(m1 - mn);
        float e  = __expf(s1 - mn);
        ss1 = ss1*al + ((p==0) ? e : 0.f);
#pragma unroll
        for (int j=0;j<16;j++) acc1[j] = fmaf(e, r[j], acc1[j]*al);
        m1 = mn;
      }
    }
    // wave-level reduce to scratch
    float bm0 = m0, bm1 = m1;
#pragma unroll
    for (int off=32; off; off>>=1){ bm0 = fmaxf(bm0, __shfl_xor(bm0, off)); bm1 = fmaxf(bm1, __shfl_xor(bm1, off)); }
    float sc0 = __expf(m0 - bm0), sc1 = __expf(m1 - bm1);
    ss0 *= sc0; ss1 *= sc1;
#pragma unroll
    for (int j=0;j<16;j++){ acc0[j] *= sc0; acc1[j] *= sc1; }
#pragma unroll
    for (int off=32; off; off>>=1){ ss0 += __shfl_xor(ss0, off); ss1 += __shfl_xor(ss1, off); }
#pragma unroll
    for (int off=2; off<=32; off<<=1){
#pragma unroll
      for (int j=0;j<16;j++){ acc0[j] += __shfl_xor(acc0[j], off); acc1[j] += __shfl_xor(acc1[j], off); }
    }
    int wid = tid >> 6;
    if ((tid&63) < 2){
#pragma unroll
      for (int j=0;j<16;j++){ wacc[0][wid][p*16+j] = acc0[j]; wacc[1][wid][p*16+j] = acc1[j]; }
    }
    if ((tid&63)==0){ wms[wid][0]=bm0; wms[wid][1]=bm1; wssL[wid][0]=ss0; wssL[wid][1]=ss1; }
    __syncthreads();
    // block-level partial -> pbuf
    if (tid < 64){
      int d = tid>>5, c = tid&31;
      float M = -3.0e38f;
#pragma unroll
      for (int w=0;w<16;w++) M = fmaxf(M, wms[w][d]);
      float S = 0.f, A = 0.f;
#pragma unroll
      for (int w=0;w<16;w++){
        float wgt = __expf(wms[w][d] - M);
        S = fmaf(wssL[w][d], wgt, S);
        A = fmaf(wacc[d][w][c], wgt, A);
      }
      float* pp = pbuf + (size_t)((b*2 + q)*2 + d)*34;
      pp[2+c] = A;
      if (c==0){ pp[0] = M; pp[1] = S; }
    }
    __syncthreads();
    if (tid==0){
      __threadfence();
      __hip_atomic_store(&flagA[b*2+q], (unsigned)(t+1), __ATOMIC_RELEASE, __HIP_MEMORY_SCOPE_AGENT);
      unsigned it = 0;
      while (__hip_atomic_load(&flagA[b*2+(1-q)], __ATOMIC_ACQUIRE, __HIP_MEMORY_SCOPE_AGENT) != (unsigned)(t+1) && it < 20000000u) ++it;
      __threadfence();
    }
    __syncthreads();
    // combine halves -> ctx
    if (tid < 64){
      int d = tid>>5, c = tid&31;
      const float* p0 = pbuf + (size_t)((b*2 + 0)*2 + d)*34;
      const float* p1 = pbuf + (size_t)((b*2 + 1)*2 + d)*34;
      float M  = fmaxf(p0[0], p1[0]);
      float w0 = __expf(p0[0]-M), w1 = __expf(p1[0]-M);
      float S  = w0*p0[1] + w1*p1[1];
      ctx[d][c] = (w0*p0[2+c] + w1*p1[2+c]) / S;
    }
    __syncthreads();

    // -- phase 3: gates for dir q (row = tid) --
    float g = bsum;
#pragma unroll
    for (int c8=0;c8<4;c8++){
      uint4 wv = wihT[(size_t)q*4096 + c8*1024 + tid];
      float4 x0 = *(const float4*)&ctx[q][c8*8];
      float4 x1 = *(const float4*)&ctx[q][c8*8+4];
      GATE8(g, wv, x0, x1)
    }
#pragma unroll 4
    for (int j8=0;j8<32;j8++){
      uint4 wv = whp[j8*1024 + tid];
      float4 h0 = *(const float4*)&hls[q][j8*8];
      float4 h1 = *(const float4*)&hls[q][j8*8+4];
      GATE8(g, wv, h0, h1)
    }
    gls[tid] = g;
    __syncthreads();
    if (tid < 256){
      float ii = sigf(gls[tid]);
      float ff = sigf(gls[256+tid]);
      float gg = tanhf(gls[512+tid]);
      float oo = sigf(gls[768+tid]);
      creg = fmaf(ff, creg, ii*gg);
      float hn = oo * tanhf(creg);
      hls[q][tid] = hn;
      int tout = q ? (59 - t) : t;
      d2in[((size_t)b*60 + tout)*512 + q*256 + tid] = hn;
      hbuf[((size_t)b*2 + q)*256 + tid] = hn;
    }
    __syncthreads();
    if (tid==0){
      __threadfence();
      __hip_atomic_store(&flagB[b*2+q], (unsigned)(t+1), __ATOMIC_RELEASE, __HIP_MEMORY_SCOPE_AGENT);
      unsigned it = 0;
      while (__hip_atomic_load(&flagB[b*2+(1-q)], __ATOMIC_ACQUIRE, __HIP_MEMORY_SCOPE_AGENT) != (unsigned)(t+1) && it < 20000000u) ++it;
      __threadfence();
    }
    __syncthreads();
    if (tid < 256) hls[1-q][tid] = hbuf[((size_t)b*2 + (1-q))*256 + tid];
    __syncthreads();
  }
}

// ---------------- generic fp32 GEMM ----------------
__global__ __launch_bounds__(256) void k_gemm(
    const float* __restrict__ A, const float* __restrict__ W,
    float* __restrict__ C, const float* __restrict__ b1, const float* __restrict__ b2,
    int K, int ldc, size_t sW, size_t sC, int sB)
{
  int m0 = blockIdx.x * 128, n0 = blockIdx.y * 128, z = blockIdx.z;
  const float* Wz = W + (size_t)z*sW;
  float* Cz = C + (size_t)z*sC;
  const float* b1z = b1 + (size_t)z*sB;
  const float* b2z = b2 ? (b2 + (size_t)z*sB) : nullptr;
  __shared__ __align__(16) float As[16][132];
  __shared__ __align__(16) float Bs[16][132];
  int tid = threadIdx.x;
  int tx = tid & 15, ty = tid >> 4;
  int r = tid >> 2, c4 = tid & 3;
  float acc[8][8] = {};
  for (int k0=0; k0<K; k0+=16){
#pragma unroll
    for (int h=0; h<2; h++){
      int rr = r + h*64;
      float4 av = *(const float4*)(A  + (size_t)(m0+rr)*K + k0 + c4*4);
      float4 bv = *(const float4*)(Wz + (size_t)(n0+rr)*K + k0 + c4*4);
      As[c4*4+0][rr]=av.x; As[c4*4+1][rr]=av.y; As[c4*4+2][rr]=av.z; As[c4*4+3][rr]=av.w;
      Bs[c4*4+0][rr]=bv.x; Bs[c4*4+1][rr]=bv.y; Bs[c4*4+2][rr]=bv.z; Bs[c4*4+3][rr]=bv.w;
    }
    __syncthreads();
#pragma unroll
    for (int kk=0; kk<16; kk++){
      float a[8], bb[8];
      *(float4*)&a[0]  = *(const float4*)&As[kk][ty*8];
      *(float4*)&a[4]  = *(const float4*)&As[kk][ty*8+4];
      *(float4*)&bb[0] = *(const float4*)&Bs[kk][tx*8];
      *(float4*)&bb[4] = *(const float4*)&Bs[kk][tx*8+4];
#pragma unroll
      for (int i=0;i<8;i++)
#pragma unroll
        for (int j=0;j<8;j++)
          acc[i][j] = fmaf(a[i], bb[j], acc[i][j]);
    }
    __syncthreads();
  }
  float bb1[8];
#pragma unroll
  for (int j=0;j<8;j++){
    int n = n0 + tx*8 + j;
    bb1[j] = b1z[n] + (b2z ? b2z[n] : 0.f);
  }
#pragma unroll
  for (int i=0;i<8;i++){
    int m = m0 + ty*8 + i;
    float o[8];
#pragma unroll
    for (int j=0;j<8;j++) o[j] = acc[i][j] + bb1[j];
    *(float4*)(Cz + (size_t)m*ldc + n0 + tx*8)     = *(const float4*)&o[0];
    *(float4*)(Cz + (size_t)m*ldc + n0 + tx*8 + 4) = *(const float4*)&o[4];
  }
}

// ---------------- dec2: recurrent, block = (dir, batch), 16 waves ----------------
__global__ __launch_bounds__(1024) void k_rec2(
    const float* __restrict__ xg,   // [2][64][60][1024]
    const uint4* __restrict__ wT,   // [2][32][1024] bf16x8
    float* __restrict__ out)        // [64][60][512]
{
  int b = blockIdx.x, d = blockIdx.y, tid = threadIdx.x;
  __shared__ __align__(16) float hls[256];
  __shared__ float gls[1024];
  float c = 0.f;
  if (tid < 256) hls[tid] = 0.f;
  __syncthreads();
  const uint4* wp = wT + (size_t)d*32*1024;
  const float* xp = xg + (((size_t)d*64 + b)*60)*1024;
  for (int step=0; step<TDEC; step++){
    int t = d ? (TDEC-1-step) : step;
    float g = xp[(size_t)t*1024 + tid];
#pragma unroll 4
    for (int j8=0;j8<32;j8++){
      uint4 wv = wp[j8*1024 + tid];
      float4 h0 = *(const float4*)&hls[j8*8];
      float4 h1 = *(const float4*)&hls[j8*8+4];
      GATE8(g, wv, h0, h1)
    }
    gls[tid] = g;
    __syncthreads();
    if (tid < 256){
      float ii = sigf(gls[tid]);
      float ff = sigf(gls[256+tid]);
      float gg = tanhf(gls[512+tid]);
      float oo = sigf(gls[768+tid]);
      c = fmaf(ff, c, ii*gg);
      float hn = oo * tanhf(c);
      hls[tid] = hn;
      out[((size_t)b*60 + t)*512 + d*256 + tid] = hn;
    }
    __syncthreads();
  }
}

extern "C" void kernel_launch(void* const* d_in, const int* in_sizes, int n_in,
                              void* d_out, int out_size, void* d_ws, size_t ws_size,
                              hipStream_t stream) {
  const float* x      = (const float*)d_in[0];
  const float* cw1    = (const float*)d_in[1];
  const float* cb1    = (const float*)d_in[2];
  const float* cw2    = (const float*)d_in[3];
  const float* cb2    = (const float*)d_in[4];
  const float* cw3    = (const float*)d_in[5];
  const float* cb3    = (const float*)d_in[6];
  const float* attn_w = (const float*)d_in[7];
  // d_in[8] attn_b: constant over softmax axis -> drops out analytically
  const float* d1_wih = (const float*)d_in[9];
  const float* d1_whh = (const float*)d_in[10];
  const float* d1_bih = (const float*)d_in[11];
  const float* d1_bhh = (const float*)d_in[12];
  const float* w2_ih0 = (const float*)d_in[13];
  const float* w2_hh0 = (const float*)d_in[14];
  const float* b2_ih0 = (const float*)d_in[15];
  const float* b2_hh0 = (const float*)d_in[16];
  const float* w2_ih1 = (const float*)d_in[17];
  const float* w2_hh1 = (const float*)d_in[18];
  const float* b2_ih1 = (const float*)d_in[19];
  const float* b2_hh1 = (const float*)d_in[20];
  const float* out_w  = (const float*)d_in[21];
  const float* out_b  = (const float*)d_in[22];

  char* ws = (char*)d_ws;
  size_t off = 0;
  unsigned* enc = (unsigned*)(ws + off); off += 16675840;          // bf16 enc, padded
  size_t off_h1 = off;
  float* h1buf = (float*)(ws + off); off += 8382464;               // (B,4093,8)
  float* h2buf = (float*)(ws + off); off += 16736256;              // (B,4086,16)
  float* d2in  = (float*)(ws + off_h1);                            // reuse: (B,60,512)
  float* l0    = (float*)(ws + off_h1 + 7864320);
  float* l1    = (float*)(ws + off_h1 + 15728640);
  uint4* wT    = (uint4*)(ws + off_h1 + 23592960);                 // 1MB dec2 pack (dead tail)
  float* xg    = (float*)(ws + off); off += 31457280;              // [2][B][60][1024]
  // dec1 packs live INSIDE the xg region (xg written only after dec1 completes)
  uint4* d1whhT = (uint4*)xg;                                      // 1 MB
  uint4* d1wihT = (uint4*)((char*)xg + 1048576);                   // +128 KB
  float* pbuf   = (float*)(ws + off); off += 64*2*2*34*4;          // 34,816 B
  float* hbuf   = (float*)(ws + off); off += 131072;               // [B][2][256]
  unsigned* flagA = (unsigned*)(ws + off); off += 512;             // [B][2]
  unsigned* flagB = (unsigned*)(ws + off); off += 512;
  (void)ws_size; (void)in_sizes; (void)n_in; (void)out_size;

  hipMemsetAsync(flagA, 0, 1024, stream);   // flagA+flagB contiguous

  // dec1 weight packs (before dec1; clobbered later by xg — fine)
  k_packw2<<<256,256,0,stream>>>(d1_whh, d1whhT, 256);
  k_packw2<<<32, 256,0,stream>>>(d1_wih, d1wihT, 32);

  int g1 = (B_*L1C + 255)/256;
  k_conv<64,8,4,false><<<g1,256,0,stream>>>(x, cw1, cb1, h1buf, 4096, L1C);
  int g2 = (B_*L2C + 255)/256;
  k_conv<8,16,8,false><<<g2,256,0,stream>>>(h1buf, cw2, cb2, h2buf, L1C, L2C);
  int g3 = (B_*L3C + 255)/256;
  k_conv<16,32,16,true><<<g3,256,0,stream>>>(h2buf, cw3, cb3, enc, L2C, L3C);

  // dec1: 128 blocks = (b, L-half); enc in LDS; twin-block sync via device atomics
  k_dec1e<<<dim3(128),1024,0,stream>>>(enc, attn_w, d1wihT, d1whhT,
                                       d1_bih, d1_bhh, d2in, pbuf, hbuf, flagA, flagB);

  // dec2 layer 0
  k_packw2<<<256,256,0,stream>>>(w2_hh0, wT, 256);
  k_gemm<<<dim3(30,8,2),256,0,stream>>>(d2in, w2_ih0, xg, b2_ih0, b2_hh0,
                                        512, 1024, (size_t)1024*512, (size_t)3840*1024, 1024);
  k_rec2<<<dim3(64,2),1024,0,stream>>>(xg, wT, l0);
  // dec2 layer 1
  k_packw2<<<256,256,0,stream>>>(w2_hh1, wT, 256);
  k_gemm<<<dim3(30,8,2),256,0,stream>>>(l0, w2_ih1, xg, b2_ih1, b2_hh1,
                                        512, 1024, (size_t)1024*512, (size_t)3840*1024, 1024);
  k_rec2<<<dim3(64,2),1024,0,stream>>>(xg, wT, l1);
  // output projection
  k_gemm<<<dim3(30,1,1),256,0,stream>>>(l1, out_w, (float*)d_out, out_b, nullptr,
                                        512, 128, 0, 0, 0);
}

// Round 9
// 4050.127 us; speedup vs baseline: 1.4661x; 1.1201x over previous
//
#include <hip/hip_runtime.h>

#define B_    64
#define L1C   4093
#define L2C   4086
#define L3C   4071
#define TDEC  60

static __device__ __forceinline__ float sigf(float x){ return 1.f/(1.f + __expf(-x)); }
static __device__ __forceinline__ unsigned f2bf(float f){
  unsigned u = __float_as_uint(f);
  u = u + 0x7fffu + ((u >> 16) & 1u);   // RNE to bf16
  return (u >> 16);
}
static __device__ __forceinline__ float bfl(unsigned u){ return __uint_as_float(u<<16); }
static __device__ __forceinline__ float bfh(unsigned u){ return __uint_as_float(u & 0xffff0000u); }

// ---------------- conv stack (conv1, conv2: fp32 out) ----------------
template<int CIN,int COUT,int KW>
__global__ __launch_bounds__(256) void k_conv(
    const float* __restrict__ in, const float* __restrict__ w,
    const float* __restrict__ bias, float* __restrict__ outp,
    int Lin_, int Lout_)
{
  int g = blockIdx.x*256 + threadIdx.x;
  int bi = g / Lout_;
  int l  = g - bi*Lout_;
  if (bi >= B_) return;
  float acc[COUT];
#pragma unroll
  for (int o=0;o<COUT;o++) acc[o] = bias[o];
  const float* ip = in + ((size_t)bi*Lin_ + l)*CIN;
  for (int k=0;k<KW;k++){
#pragma unroll
    for (int i4=0;i4<CIN/4;i4++){
      float4 xv = *(const float4*)(ip + k*CIN + i4*4);
#pragma unroll
      for (int c=0;c<4;c++){
        float xs = (&xv.x)[c];
        int i = i4*4+c;
#pragma unroll
        for (int o=0;o<COUT;o++)
          acc[o] = fmaf(xs, w[(o*CIN + i)*KW + k], acc[o]);
      }
    }
  }
  float* op = outp + ((size_t)bi*Lout_ + l)*COUT;
#pragma unroll
  for (int o=0;o<COUT;o++) op[o] = fmaxf(acc[o],0.f);
}

// ---------------- conv3: relu + row-quantize to u8 (scale = rowmax/255) ----------------
__global__ __launch_bounds__(256) void k_conv3q(
    const float* __restrict__ in, const float* __restrict__ w,
    const float* __restrict__ bias, uint4* __restrict__ encq,
    float* __restrict__ encs, int Lin_, int Lout_)
{
  int g = blockIdx.x*256 + threadIdx.x;
  int bi = g / Lout_;
  int l  = g - bi*Lout_;
  if (bi >= B_) return;
  float acc[32];
#pragma unroll
  for (int o=0;o<32;o++) acc[o] = bias[o];
  const float* ip = in + ((size_t)bi*Lin_ + l)*16;
  for (int k=0;k<16;k++){
#pragma unroll
    for (int i4=0;i4<4;i4++){
      float4 xv = *(const float4*)(ip + k*16 + i4*4);
#pragma unroll
      for (int c=0;c<4;c++){
        float xs = (&xv.x)[c];
        int i = i4*4+c;
#pragma unroll
        for (int o=0;o<32;o++)
          acc[o] = fmaf(xs, w[(o*16 + i)*16 + k], acc[o]);
      }
    }
  }
  float mx = 0.f;
#pragma unroll
  for (int o=0;o<32;o++){ acc[o] = fmaxf(acc[o],0.f); mx = fmaxf(mx, acc[o]); }
  float scale = mx * (1.f/255.f);
  float inv = (mx > 0.f) ? (255.f/mx) : 0.f;
  unsigned qs[8];
#pragma unroll
  for (int q8=0;q8<8;q8++){
    unsigned q0 = (unsigned)(acc[q8*4+0]*inv + 0.5f);
    unsigned q1 = (unsigned)(acc[q8*4+1]*inv + 0.5f);
    unsigned q2 = (unsigned)(acc[q8*4+2]*inv + 0.5f);
    unsigned q3 = (unsigned)(acc[q8*4+3]*inv + 0.5f);
    qs[q8] = q0 | (q1<<8) | (q2<<16) | (q3<<24);
  }
  uint4* op = encq + ((size_t)bi*Lout_ + l)*2;
  op[0] = make_uint4(qs[0],qs[1],qs[2],qs[3]);
  op[1] = make_uint4(qs[4],qs[5],qs[6],qs[7]);
  encs[(size_t)bi*Lout_ + l] = scale;
}

// ---------------- pack weights: [2][1024][K] fp32 -> [2][K/8][1024] bf16x8 ----------------
__global__ __launch_bounds__(256) void k_packw2(
    const float* __restrict__ w, uint4* __restrict__ wT, int K)
{
  int gid = blockIdx.x*256 + threadIdx.x;
  int per = (K/8)*1024;
  int d = gid / per, rem = gid - d*per;
  int j8 = rem >> 10, row = rem & 1023;
  const float* src = w + ((size_t)d*1024 + row)*K + j8*8;
  float4 a = *(const float4*)src;
  float4 b = *(const float4*)(src+4);
  uint4 o;
  o.x = f2bf(a.x) | (f2bf(a.y)<<16);
  o.y = f2bf(a.z) | (f2bf(a.w)<<16);
  o.z = f2bf(b.x) | (f2bf(b.y)<<16);
  o.w = f2bf(b.z) | (f2bf(b.w)<<16);
  wT[gid] = o;
}

#define GATE8(gv, wv, hh0, hh1) \
  gv = fmaf(bfl(wv.x), hh0.x, gv); gv = fmaf(bfh(wv.x), hh0.y, gv); \
  gv = fmaf(bfl(wv.y), hh0.z, gv); gv = fmaf(bfh(wv.y), hh0.w, gv); \
  gv = fmaf(bfl(wv.z), hh1.x, gv); gv = fmaf(bfh(wv.z), hh1.y, gv); \
  gv = fmaf(bfl(wv.w), hh1.z, gv); gv = fmaf(bfh(wv.w), hh1.w, gv);

// ---------------- dec1: block=(b,d); FULL enc slice resident in LDS as u8+rowscale ----------------
// 128 blocks x 1024 thr, fully independent (no inter-block traffic, no fences).
// Flash single pass per step over 4071 LDS rows; whh streamed bf16 (L2-hot, proven).
__global__ __launch_bounds__(1024) void k_dec1f(
    const uint4* __restrict__ encq,        // [B][L3C][2] uint4 (32 x u8)
    const float* __restrict__ encs,        // [B][L3C] rowscale
    const float* __restrict__ attn_w,      // [256][32]
    const uint4* __restrict__ wihT,        // [2][4][1024] bf16x8 (K=32)
    const uint4* __restrict__ whhT,        // [2][32][1024] bf16x8 (K=256)
    const float* __restrict__ bih, const float* __restrict__ bhh,
    float* __restrict__ d2in)              // [B][60][512]
{
  int b = blockIdx.x, d = blockIdx.y, tid = threadIdx.x;
  int p = tid & 1, rb = tid >> 1;          // pair covers rows rb+512k, k=0..7

  __shared__ __align__(16) uint4 encQ[8192];   // 128 KB (rows 0..4095, tail zero)
  __shared__ float sls[4096];                  // 16 KB rowscales
  __shared__ __align__(16) float hls[256];
  __shared__ float vl[32];
  __shared__ float red[1024];
  __shared__ float scr[512];                   // [16 waves][32 ch]
  __shared__ __align__(16) float ctx[32];
  __shared__ float gls[1024];

  { // stage enc slice once
    const uint4* src = encq + (size_t)b*L3C*2;
    for (int i = tid; i < 8192; i += 1024)
      encQ[i] = (i < L3C*2) ? src[i] : make_uint4(0,0,0,0);
    const float* ss = encs + (size_t)b*L3C;
    for (int i = tid; i < 4096; i += 1024)
      sls[i] = (i < L3C) ? ss[i] : 0.f;
  }
  if (tid < 256) hls[tid] = 0.f;
  float creg = 0.f;
  float bsum = bih[(size_t)d*1024 + tid] + bhh[(size_t)d*1024 + tid];
  const uint4* whp = whhT + (size_t)d*32768;
  __syncthreads();

  for (int t=0; t<TDEC; t++){
    // -- phase 1: v[c] = sum_u h[u]*attn_w[u][c] --
    {
      int c = tid & 31, part = tid >> 5;
      const float* wp = attn_w + (size_t)(part*8)*32 + c;
      float s = 0.f;
#pragma unroll
      for (int k=0;k<8;k++) s = fmaf(hls[part*8+k], wp[k*32], s);
      red[tid] = s;
    }
    __syncthreads();
    if (tid < 32){
      float v = 0.f;
#pragma unroll
      for (int q=0;q<32;q++) v += red[q*32 + tid];
      vl[tid] = v;
    }
    __syncthreads();

    // -- phase 2: flash single pass over LDS rows (my 16 channels) --
    float vreg[16];
#pragma unroll
    for (int j=0;j<16;j++) vreg[j] = vl[p*16 + j];
    float mloc = -3.0e38f, ssum = 0.f;
    float acc[16];
#pragma unroll
    for (int j=0;j<16;j++) acc[j] = 0.f;
#pragma unroll
    for (int k=0;k<8;k++){
      int l = rb + 512*k;
      bool valid = (l < L3C);
      uint4 qv = encQ[l*2 + p];
      float s_l = sls[l];
      float r[16];
      r[0]=(float)( qv.x      & 255u); r[1]=(float)((qv.x>>8 ) & 255u);
      r[2]=(float)((qv.x>>16) & 255u); r[3]=(float)((qv.x>>24)       );
      r[4]=(float)( qv.y      & 255u); r[5]=(float)((qv.y>>8 ) & 255u);
      r[6]=(float)((qv.y>>16) & 255u); r[7]=(float)((qv.y>>24)       );
      r[8]=(float)( qv.z      & 255u); r[9]=(float)((qv.z>>8 ) & 255u);
      r[10]=(float)((qv.z>>16) & 255u); r[11]=(float)((qv.z>>24)      );
      r[12]=(float)( qv.w      & 255u); r[13]=(float)((qv.w>>8 ) & 255u);
      r[14]=(float)((qv.w>>16) & 255u); r[15]=(float)((qv.w>>24)      );
      float s = 0.f;
#pragma unroll
      for (int j=0;j<16;j++) s = fmaf(r[j], vreg[j], s);
      s += __shfl_xor(s, 1);                 // combine parity halves (q-dot)
      s = valid ? (s * s_l) : -3.0e38f;      // apply rowscale to score
      float mnew = fmaxf(mloc, s);
      float al = __expf(mloc - mnew);
      float e  = __expf(s - mnew);
      ssum = ssum*al + ((p==0) ? e : 0.f);
      float em = e * s_l;                    // fold rowscale into ctx accum
#pragma unroll
      for (int j=0;j<16;j++) acc[j] = fmaf(em, r[j], acc[j]*al);
      mloc = mnew;
    }
    // block max
    float m = mloc;
#pragma unroll
    for (int off=32; off; off>>=1) m = fmaxf(m, __shfl_xor(m, off));
    int wid = tid >> 6;
    if ((tid&63)==0) red[wid] = m;
    __syncthreads();
    m = red[0];
#pragma unroll
    for (int i=1;i<16;i++) m = fmaxf(m, red[i]);
    float sc = __expf(mloc - m);
    ssum *= sc;
#pragma unroll
    for (int j=0;j<16;j++) acc[j] *= sc;
#pragma unroll
    for (int off=32; off; off>>=1) ssum += __shfl_xor(ssum, off);
    if ((tid&63)==0) red[16 + wid] = ssum;
#pragma unroll
    for (int off=2; off<=32; off<<=1){
#pragma unroll
      for (int j=0;j<16;j++) acc[j] += __shfl_xor(acc[j], off);
    }
    if ((tid&63) < 2){
#pragma unroll
      for (int j=0;j<16;j++) scr[wid*32 + p*16 + j] = acc[j];
    }
    __syncthreads();
    if (tid < 32){
      float S = 0.f, s2 = 0.f;
#pragma unroll
      for (int w=0;w<16;w++){ S += red[16+w]; s2 += scr[w*32 + tid]; }
      ctx[tid] = s2 / S;
    }
    __syncthreads();

    // -- phase 3: LSTM gates (row = tid) --
    float g = bsum;
#pragma unroll
    for (int c8=0;c8<4;c8++){
      uint4 wv = wihT[(size_t)d*4096 + c8*1024 + tid];
      float4 x0 = *(const float4*)&ctx[c8*8];
      float4 x1 = *(const float4*)&ctx[c8*8+4];
      GATE8(g, wv, x0, x1)
    }
#pragma unroll 4
    for (int j8=0;j8<32;j8++){
      uint4 wv = whp[j8*1024 + tid];
      float4 h0 = *(const float4*)&hls[j8*8];
      float4 h1 = *(const float4*)&hls[j8*8+4];
      GATE8(g, wv, h0, h1)
    }
    gls[tid] = g;
    __syncthreads();
    if (tid < 256){
      float ii = sigf(gls[tid]);
      float ff = sigf(gls[256+tid]);
      float gg = tanhf(gls[512+tid]);
      float oo = sigf(gls[768+tid]);
      creg = fmaf(ff, creg, ii*gg);
      float hn = oo * tanhf(creg);
      hls[tid] = hn;
      int tout = d ? (59 - t) : t;
      d2in[((size_t)b*60 + tout)*512 + d*256 + tid] = hn;
    }
    __syncthreads();
  }
}

// ---------------- generic fp32 GEMM ----------------
__global__ __launch_bounds__(256) void k_gemm(
    const float* __restrict__ A, const float* __restrict__ W,
    float* __restrict__ C, const float* __restrict__ b1, const float* __restrict__ b2,
    int K, int ldc, size_t sW, size_t sC, int sB)
{
  int m0 = blockIdx.x * 128, n0 = blockIdx.y * 128, z = blockIdx.z;
  const float* Wz = W + (size_t)z*sW;
  float* Cz = C + (size_t)z*sC;
  const float* b1z = b1 + (size_t)z*sB;
  const float* b2z = b2 ? (b2 + (size_t)z*sB) : nullptr;
  __shared__ __align__(16) float As[16][132];
  __shared__ __align__(16) float Bs[16][132];
  int tid = threadIdx.x;
  int tx = tid & 15, ty = tid >> 4;
  int r = tid >> 2, c4 = tid & 3;
  float acc[8][8] = {};
  for (int k0=0; k0<K; k0+=16){
#pragma unroll
    for (int h=0; h<2; h++){
      int rr = r + h*64;
      float4 av = *(const float4*)(A  + (size_t)(m0+rr)*K + k0 + c4*4);
      float4 bv = *(const float4*)(Wz + (size_t)(n0+rr)*K + k0 + c4*4);
      As[c4*4+0][rr]=av.x; As[c4*4+1][rr]=av.y; As[c4*4+2][rr]=av.z; As[c4*4+3][rr]=av.w;
      Bs[c4*4+0][rr]=bv.x; Bs[c4*4+1][rr]=bv.y; Bs[c4*4+2][rr]=bv.z; Bs[c4*4+3][rr]=bv.w;
    }
    __syncthreads();
#pragma unroll
    for (int kk=0; kk<16; kk++){
      float a[8], bb[8];
      *(float4*)&a[0]  = *(const float4*)&As[kk][ty*8];
      *(float4*)&a[4]  = *(const float4*)&As[kk][ty*8+4];
      *(float4*)&bb[0] = *(const float4*)&Bs[kk][tx*8];
      *(float4*)&bb[4] = *(const float4*)&Bs[kk][tx*8+4];
#pragma unroll
      for (int i=0;i<8;i++)
#pragma unroll
        for (int j=0;j<8;j++)
          acc[i][j] = fmaf(a[i], bb[j], acc[i][j]);
    }
    __syncthreads();
  }
  float bb1[8];
#pragma unroll
  for (int j=0;j<8;j++){
    int n = n0 + tx*8 + j;
    bb1[j] = b1z[n] + (b2z ? b2z[n] : 0.f);
  }
#pragma unroll
  for (int i=0;i<8;i++){
    int m = m0 + ty*8 + i;
    float o[8];
#pragma unroll
    for (int j=0;j<8;j++) o[j] = acc[i][j] + bb1[j];
    *(float4*)(Cz + (size_t)m*ldc + n0 + tx*8)     = *(const float4*)&o[0];
    *(float4*)(Cz + (size_t)m*ldc + n0 + tx*8 + 4) = *(const float4*)&o[4];
  }
}

// ---------------- dec2: recurrent, block = (dir, batch), 16 waves ----------------
__global__ __launch_bounds__(1024) void k_rec2(
    const float* __restrict__ xg,   // [2][64][60][1024]
    const uint4* __restrict__ wT,   // [2][32][1024] bf16x8
    float* __restrict__ out)        // [64][60][512]
{
  int b = blockIdx.x, d = blockIdx.y, tid = threadIdx.x;
  __shared__ __align__(16) float hls[256];
  __shared__ float gls[1024];
  float c = 0.f;
  if (tid < 256) hls[tid] = 0.f;
  __syncthreads();
  const uint4* wp = wT + (size_t)d*32*1024;
  const float* xp = xg + (((size_t)d*64 + b)*60)*1024;
  for (int step=0; step<TDEC; step++){
    int t = d ? (TDEC-1-step) : step;
    float g = xp[(size_t)t*1024 + tid];
#pragma unroll 4
    for (int j8=0;j8<32;j8++){
      uint4 wv = wp[j8*1024 + tid];
      float4 h0 = *(const float4*)&hls[j8*8];
      float4 h1 = *(const float4*)&hls[j8*8+4];
      GATE8(g, wv, h0, h1)
    }
    gls[tid] = g;
    __syncthreads();
    if (tid < 256){
      float ii = sigf(gls[tid]);
      float ff = sigf(gls[256+tid]);
      float gg = tanhf(gls[512+tid]);
      float oo = sigf(gls[768+tid]);
      c = fmaf(ff, c, ii*gg);
      float hn = oo * tanhf(c);
      hls[tid] = hn;
      out[((size_t)b*60 + t)*512 + d*256 + tid] = hn;
    }
    __syncthreads();
  }
}

extern "C" void kernel_launch(void* const* d_in, const int* in_sizes, int n_in,
                              void* d_out, int out_size, void* d_ws, size_t ws_size,
                              hipStream_t stream) {
  const float* x      = (const float*)d_in[0];
  const float* cw1    = (const float*)d_in[1];
  const float* cb1    = (const float*)d_in[2];
  const float* cw2    = (const float*)d_in[3];
  const float* cb2    = (const float*)d_in[4];
  const float* cw3    = (const float*)d_in[5];
  const float* cb3    = (const float*)d_in[6];
  const float* attn_w = (const float*)d_in[7];
  // d_in[8] attn_b: constant over softmax axis -> drops out analytically
  const float* d1_wih = (const float*)d_in[9];
  const float* d1_whh = (const float*)d_in[10];
  const float* d1_bih = (const float*)d_in[11];
  const float* d1_bhh = (const float*)d_in[12];
  const float* w2_ih0 = (const float*)d_in[13];
  const float* w2_hh0 = (const float*)d_in[14];
  const float* b2_ih0 = (const float*)d_in[15];
  const float* b2_hh0 = (const float*)d_in[16];
  const float* w2_ih1 = (const float*)d_in[17];
  const float* w2_hh1 = (const float*)d_in[18];
  const float* b2_ih1 = (const float*)d_in[19];
  const float* b2_hh1 = (const float*)d_in[20];
  const float* out_w  = (const float*)d_in[21];
  const float* out_b  = (const float*)d_in[22];

  char* ws = (char*)d_ws;
  size_t off = 0;
  // enc region (reuses old 16.67 MB footprint): u8 enc (8.34 MB) + rowscales (1.04 MB)
  uint4* encq = (uint4*)(ws + off);                                // [B][L3C][2] uint4
  float* encs = (float*)(ws + off + 8338432);                      // [B][L3C]
  off += 16675840;
  size_t off_h1 = off;
  float* h1buf = (float*)(ws + off); off += 8382464;               // (B,4093,8)
  float* h2buf = (float*)(ws + off); off += 16736256;              // (B,4086,16)
  float* d2in  = (float*)(ws + off_h1);                            // reuse: (B,60,512)
  float* l0    = (float*)(ws + off_h1 + 7864320);
  float* l1    = (float*)(ws + off_h1 + 15728640);
  uint4* wT    = (uint4*)(ws + off_h1 + 23592960);                 // 1MB dec2 pack (dead tail)
  float* xg    = (float*)(ws + off); off += 31457280;              // [2][B][60][1024]
  // dec1 packs live INSIDE the xg region (xg written only after dec1 completes)
  uint4* d1whhT = (uint4*)xg;                                      // 1 MB
  uint4* d1wihT = (uint4*)((char*)xg + 1048576);                   // +128 KB
  (void)ws_size; (void)in_sizes; (void)n_in; (void)out_size;

  // dec1 weight packs (before dec1; clobbered later by xg — fine)
  k_packw2<<<256,256,0,stream>>>(d1_whh, d1whhT, 256);
  k_packw2<<<32, 256,0,stream>>>(d1_wih, d1wihT, 32);

  int g1 = (B_*L1C + 255)/256;
  k_conv<64,8,4><<<g1,256,0,stream>>>(x, cw1, cb1, h1buf, 4096, L1C);
  int g2 = (B_*L2C + 255)/256;
  k_conv<8,16,8><<<g2,256,0,stream>>>(h1buf, cw2, cb2, h2buf, L1C, L2C);
  int g3 = (B_*L3C + 255)/256;
  k_conv3q<<<g3,256,0,stream>>>(h2buf, cw3, cb3, encq, encs, L2C, L3C);

  // dec1: 128 independent blocks (b,d); enc u8-resident in LDS; no inter-block sync
  k_dec1f<<<dim3(64,2),1024,0,stream>>>(encq, encs, attn_w, d1wihT, d1whhT,
                                        d1_bih, d1_bhh, d2in);

  // dec2 layer 0
  k_packw2<<<256,256,0,stream>>>(w2_hh0, wT, 256);
  k_gemm<<<dim3(30,8,2),256,0,stream>>>(d2in, w2_ih0, xg, b2_ih0, b2_hh0,
                                        512, 1024, (size_t)1024*512, (size_t)3840*1024, 1024);
  k_rec2<<<dim3(64,2),1024,0,stream>>>(xg, wT, l0);
  // dec2 layer 1
  k_packw2<<<256,256,0,stream>>>(w2_hh1, wT, 256);
  k_gemm<<<dim3(30,8,2),256,0,stream>>>(l0, w2_ih1, xg, b2_ih1, b2_hh1,
                                        512, 1024, (size_t)1024*512, (size_t)3840*1024, 1024);
  k_rec2<<<dim3(64,2),1024,0,stream>>>(xg, wT, l1);
  // output projection
  k_gemm<<<dim3(30,1,1),256,0,stream>>>(l1, out_w, (float*)d_out, out_b, nullptr,
                                        512, 128, 0, 0, 0);
}

// Round 10
// 2361.222 us; speedup vs baseline: 2.5148x; 1.7153x over previous
//
#include <hip/hip_runtime.h>

#define B_    64
#define L1C   4093
#define L2C   4086
#define L3C   4071
#define TDEC  60

static __device__ __forceinline__ float sigf(float x){ return 1.f/(1.f + __expf(-x)); }
static __device__ __forceinline__ unsigned f2bf(float f){
  unsigned u = __float_as_uint(f);
  u = u + 0x7fffu + ((u >> 16) & 1u);   // RNE to bf16
  return (u >> 16);
}
static __device__ __forceinline__ float bfl(unsigned u){ return __uint_as_float(u<<16); }
static __device__ __forceinline__ float bfh(unsigned u){ return __uint_as_float(u & 0xffff0000u); }

// ---------------- conv stack (conv1, conv2: fp32 out) ----------------
template<int CIN,int COUT,int KW>
__global__ __launch_bounds__(256) void k_conv(
    const float* __restrict__ in, const float* __restrict__ w,
    const float* __restrict__ bias, float* __restrict__ outp,
    int Lin_, int Lout_)
{
  int g = blockIdx.x*256 + threadIdx.x;
  int bi = g / Lout_;
  int l  = g - bi*Lout_;
  if (bi >= B_) return;
  float acc[COUT];
#pragma unroll
  for (int o=0;o<COUT;o++) acc[o] = bias[o];
  const float* ip = in + ((size_t)bi*Lin_ + l)*CIN;
  for (int k=0;k<KW;k++){
#pragma unroll
    for (int i4=0;i4<CIN/4;i4++){
      float4 xv = *(const float4*)(ip + k*CIN + i4*4);
#pragma unroll
      for (int c=0;c<4;c++){
        float xs = (&xv.x)[c];
        int i = i4*4+c;
#pragma unroll
        for (int o=0;o<COUT;o++)
          acc[o] = fmaf(xs, w[(o*CIN + i)*KW + k], acc[o]);
      }
    }
  }
  float* op = outp + ((size_t)bi*Lout_ + l)*COUT;
#pragma unroll
  for (int o=0;o<COUT;o++) op[o] = fmaxf(acc[o],0.f);
}

// ---------------- conv3: relu + row-quantize to u8 (scale = rowmax/255) ----------------
__global__ __launch_bounds__(256) void k_conv3q(
    const float* __restrict__ in, const float* __restrict__ w,
    const float* __restrict__ bias, uint4* __restrict__ encq,
    float* __restrict__ encs, int Lin_, int Lout_)
{
  int g = blockIdx.x*256 + threadIdx.x;
  int bi = g / Lout_;
  int l  = g - bi*Lout_;
  if (bi >= B_) return;
  float acc[32];
#pragma unroll
  for (int o=0;o<32;o++) acc[o] = bias[o];
  const float* ip = in + ((size_t)bi*Lin_ + l)*16;
  for (int k=0;k<16;k++){
#pragma unroll
    for (int i4=0;i4<4;i4++){
      float4 xv = *(const float4*)(ip + k*16 + i4*4);
#pragma unroll
      for (int c=0;c<4;c++){
        float xs = (&xv.x)[c];
        int i = i4*4+c;
#pragma unroll
        for (int o=0;o<32;o++)
          acc[o] = fmaf(xs, w[(o*16 + i)*16 + k], acc[o]);
      }
    }
  }
  float mx = 0.f;
#pragma unroll
  for (int o=0;o<32;o++){ acc[o] = fmaxf(acc[o],0.f); mx = fmaxf(mx, acc[o]); }
  float scale = mx * (1.f/255.f);
  float inv = (mx > 0.f) ? (255.f/mx) : 0.f;
  unsigned qs[8];
#pragma unroll
  for (int q8=0;q8<8;q8++){
    unsigned q0 = (unsigned)(acc[q8*4+0]*inv + 0.5f);
    unsigned q1 = (unsigned)(acc[q8*4+1]*inv + 0.5f);
    unsigned q2 = (unsigned)(acc[q8*4+2]*inv + 0.5f);
    unsigned q3 = (unsigned)(acc[q8*4+3]*inv + 0.5f);
    qs[q8] = q0 | (q1<<8) | (q2<<16) | (q3<<24);
  }
  uint4* op = encq + ((size_t)bi*Lout_ + l)*2;
  op[0] = make_uint4(qs[0],qs[1],qs[2],qs[3]);
  op[1] = make_uint4(qs[4],qs[5],qs[6],qs[7]);
  encs[(size_t)bi*Lout_ + l] = scale;
}

// ---------------- pack weights: [2][1024][K] fp32 -> [2][K/8][1024] bf16x8 ----------------
__global__ __launch_bounds__(256) void k_packw2(
    const float* __restrict__ w, uint4* __restrict__ wT, int K)
{
  int gid = blockIdx.x*256 + threadIdx.x;
  int per = (K/8)*1024;
  int d = gid / per, rem = gid - d*per;
  int j8 = rem >> 10, row = rem & 1023;
  const float* src = w + ((size_t)d*1024 + row)*K + j8*8;
  float4 a = *(const float4*)src;
  float4 b = *(const float4*)(src+4);
  uint4 o;
  o.x = f2bf(a.x) | (f2bf(a.y)<<16);
  o.y = f2bf(a.z) | (f2bf(a.w)<<16);
  o.z = f2bf(b.x) | (f2bf(b.y)<<16);
  o.w = f2bf(b.z) | (f2bf(b.w)<<16);
  wT[gid] = o;
}

#define GATE8(gv, wv, hh0, hh1) \
  gv = fmaf(bfl(wv.x), hh0.x, gv); gv = fmaf(bfh(wv.x), hh0.y, gv); \
  gv = fmaf(bfl(wv.y), hh0.z, gv); gv = fmaf(bfh(wv.y), hh0.w, gv); \
  gv = fmaf(bfl(wv.z), hh1.x, gv); gv = fmaf(bfh(wv.z), hh1.y, gv); \
  gv = fmaf(bfl(wv.w), hh1.z, gv); gv = fmaf(bfh(wv.w), hh1.w, gv);

#define CVT8(r, qv) \
  r[0]=(float)( qv.x      & 255u); r[1]=(float)((qv.x>>8 ) & 255u); \
  r[2]=(float)((qv.x>>16) & 255u); r[3]=(float)((qv.x>>24)       ); \
  r[4]=(float)( qv.y      & 255u); r[5]=(float)((qv.y>>8 ) & 255u); \
  r[6]=(float)((qv.y>>16) & 255u); r[7]=(float)((qv.y>>24)       );

// ---------------- dec1: block=(b,d); enc u8 in LDS; quad split (8ch/thread), static-bound softmax ----------------
// 128 independent blocks x 1024 thr. Live VGPRs/thread ~35 (fits the observed 64-cap, no spill).
// M = sum_c maxenc[c]*max(v[c],0) >= all scores  => single-pass exp(s-M), 1 FMA/ch accumulate.
__global__ __launch_bounds__(1024) void k_dec1g(
    const uint4* __restrict__ encq,        // [B][L3C][2] uint4 (32 x u8)
    const float* __restrict__ encs,        // [B][L3C] rowscale
    const float* __restrict__ attn_w,      // [256][32]
    const uint4* __restrict__ wihT,        // [2][4][1024] bf16x8 (K=32)
    const uint4* __restrict__ whhT,        // [2][32][1024] bf16x8 (K=256)
    const float* __restrict__ bih, const float* __restrict__ bhh,
    float* __restrict__ d2in)              // [B][60][512]
{
  int b = blockIdx.x, d = blockIdx.y, tid = threadIdx.x;
  int c = tid & 3, rb = tid >> 2;          // quad covers rows rb+256k, k=0..15; lane owns ch c*8..c*8+7

  __shared__ __align__(16) uint2 encQ2[16384];  // 128 KB: row l = 4 uint2 (32 x u8)
  __shared__ float sls[4096];                   // 16 KB rowscales
  __shared__ __align__(16) float hls[256];
  __shared__ float vl[32];
  __shared__ float maxenc[32];
  __shared__ float Msh;
  __shared__ float red[1024];
  __shared__ float scr[512];                    // [16 waves][32 ch]
  __shared__ __align__(16) float ctx[32];
  __shared__ float gls[1024];

  { // stage enc slice once (uint4-coalesced)
    const uint4* src = encq + (size_t)b*L3C*2;
    uint4* dst = (uint4*)encQ2;
    for (int i = tid; i < 8192; i += 1024)
      dst[i] = (i < L3C*2) ? src[i] : make_uint4(0,0,0,0);
    const float* ss = encs + (size_t)b*L3C;
    for (int i = tid; i < 4096; i += 1024)
      sls[i] = (i < L3C) ? ss[i] : 0.f;
  }
  if (tid < 256) hls[tid] = 0.f;
  float creg = 0.f;
  float bsum = bih[(size_t)d*1024 + tid] + bhh[(size_t)d*1024 + tid];
  const uint4* whp = whhT + (size_t)d*32768;
  __syncthreads();

  { // one-time: per-channel max of real enc (>=0) -> maxenc[32]
    float mc[8];
#pragma unroll
    for (int j=0;j<8;j++) mc[j] = 0.f;
#pragma unroll
    for (int k=0;k<16;k++){
      int l = rb + 256*k;
      uint2 qv = encQ2[l*4 + c];
      float sl = sls[l];
      float r[8]; CVT8(r, qv)
#pragma unroll
      for (int j=0;j<8;j++) mc[j] = fmaxf(mc[j], r[j]*sl);
    }
#pragma unroll
    for (int off=4; off<=32; off<<=1){
#pragma unroll
      for (int j=0;j<8;j++) mc[j] = fmaxf(mc[j], __shfl_xor(mc[j], off));
    }
    int wid = tid >> 6;
    if ((tid&63) < 4){
#pragma unroll
      for (int j=0;j<8;j++) scr[wid*32 + c*8 + j] = mc[j];
    }
    __syncthreads();
    if (tid < 32){
      float mm = 0.f;
#pragma unroll
      for (int w=0;w<16;w++) mm = fmaxf(mm, scr[w*32 + tid]);
      maxenc[tid] = mm;
    }
    __syncthreads();
  }

  for (int t=0; t<TDEC; t++){
    // -- phase 1: v[c] = sum_u h[u]*attn_w[u][c]; M = sum_c maxenc[c]*max(v,0) --
    {
      int cc = tid & 31, part = tid >> 5;
      const float* wp = attn_w + (size_t)(part*8)*32 + cc;
      float s = 0.f;
#pragma unroll
      for (int k=0;k<8;k++) s = fmaf(hls[part*8+k], wp[k*32], s);
      red[tid] = s;
    }
    __syncthreads();
    if (tid < 32){
      float v = 0.f;
#pragma unroll
      for (int q=0;q<32;q++) v += red[q*32 + tid];
      vl[tid] = v;
      float mt = maxenc[tid] * fmaxf(v, 0.f);
#pragma unroll
      for (int off=1; off<32; off<<=1) mt += __shfl_xor(mt, off);
      if (tid==0) Msh = mt;
    }
    __syncthreads();

    // -- phase 2: single pass, no max tracking (M is a static bound) --
    float vreg[8];
#pragma unroll
    for (int j=0;j<8;j++) vreg[j] = vl[c*8 + j];
    float M = Msh;
    float ssum = 0.f;
    float acc[8];
#pragma unroll
    for (int j=0;j<8;j++) acc[j] = 0.f;
#pragma unroll
    for (int k=0;k<16;k++){
      int l = rb + 256*k;
      uint2 qv = encQ2[l*4 + c];
      float sl = sls[l];
      float r[8]; CVT8(r, qv)
      float s = 0.f;
#pragma unroll
      for (int j=0;j<8;j++) s = fmaf(r[j], vreg[j], s);
      s += __shfl_xor(s, 1);
      s += __shfl_xor(s, 2);
      s *= sl;
      if (k==15 && l >= L3C) s = -3.0e38f;   // only last iter can be OOB
      float e = __expf(s - M);
      ssum += e;
      float em = e * sl;
#pragma unroll
      for (int j=0;j<8;j++) acc[j] = fmaf(em, r[j], acc[j]);
    }
    // reduce: quads already share rows; butterfly across quads in wave
#pragma unroll
    for (int off=4; off<=32; off<<=1){
      ssum += __shfl_xor(ssum, off);
#pragma unroll
      for (int j=0;j<8;j++) acc[j] += __shfl_xor(acc[j], off);
    }
    int wid = tid >> 6;
    if ((tid&63) < 4){
#pragma unroll
      for (int j=0;j<8;j++) scr[wid*32 + c*8 + j] = acc[j];
    }
    if ((tid&63)==0) red[wid] = ssum;
    __syncthreads();
    if (tid < 32){
      float S = 0.f, s2 = 0.f;
#pragma unroll
      for (int w=0;w<16;w++){ S += red[w]; s2 += scr[w*32 + tid]; }
      ctx[tid] = s2 / S;
    }
    __syncthreads();

    // -- phase 3: LSTM gates (row = tid) --
    float g = bsum;
#pragma unroll
    for (int c8=0;c8<4;c8++){
      uint4 wv = wihT[(size_t)d*4096 + c8*1024 + tid];
      float4 x0 = *(const float4*)&ctx[c8*8];
      float4 x1 = *(const float4*)&ctx[c8*8+4];
      GATE8(g, wv, x0, x1)
    }
#pragma unroll 4
    for (int j8=0;j8<32;j8++){
      uint4 wv = whp[j8*1024 + tid];
      float4 h0 = *(const float4*)&hls[j8*8];
      float4 h1 = *(const float4*)&hls[j8*8+4];
      GATE8(g, wv, h0, h1)
    }
    gls[tid] = g;
    __syncthreads();
    if (tid < 256){
      float ii = sigf(gls[tid]);
      float ff = sigf(gls[256+tid]);
      float gg = tanhf(gls[512+tid]);
      float oo = sigf(gls[768+tid]);
      creg = fmaf(ff, creg, ii*gg);
      float hn = oo * tanhf(creg);
      hls[tid] = hn;
      int tout = d ? (59 - t) : t;
      d2in[((size_t)b*60 + tout)*512 + d*256 + tid] = hn;
    }
    __syncthreads();
  }
}

// ---------------- generic fp32 GEMM ----------------
__global__ __launch_bounds__(256) void k_gemm(
    const float* __restrict__ A, const float* __restrict__ W,
    float* __restrict__ C, const float* __restrict__ b1, const float* __restrict__ b2,
    int K, int ldc, size_t sW, size_t sC, int sB)
{
  int m0 = blockIdx.x * 128, n0 = blockIdx.y * 128, z = blockIdx.z;
  const float* Wz = W + (size_t)z*sW;
  float* Cz = C + (size_t)z*sC;
  const float* b1z = b1 + (size_t)z*sB;
  const float* b2z = b2 ? (b2 + (size_t)z*sB) : nullptr;
  __shared__ __align__(16) float As[16][132];
  __shared__ __align__(16) float Bs[16][132];
  int tid = threadIdx.x;
  int tx = tid & 15, ty = tid >> 4;
  int r = tid >> 2, c4 = tid & 3;
  float acc[8][8] = {};
  for (int k0=0; k0<K; k0+=16){
#pragma unroll
    for (int h=0; h<2; h++){
      int rr = r + h*64;
      float4 av = *(const float4*)(A  + (size_t)(m0+rr)*K + k0 + c4*4);
      float4 bv = *(const float4*)(Wz + (size_t)(n0+rr)*K + k0 + c4*4);
      As[c4*4+0][rr]=av.x; As[c4*4+1][rr]=av.y; As[c4*4+2][rr]=av.z; As[c4*4+3][rr]=av.w;
      Bs[c4*4+0][rr]=bv.x; Bs[c4*4+1][rr]=bv.y; Bs[c4*4+2][rr]=bv.z; Bs[c4*4+3][rr]=bv.w;
    }
    __syncthreads();
#pragma unroll
    for (int kk=0; kk<16; kk++){
      float a[8], bb[8];
      *(float4*)&a[0]  = *(const float4*)&As[kk][ty*8];
      *(float4*)&a[4]  = *(const float4*)&As[kk][ty*8+4];
      *(float4*)&bb[0] = *(const float4*)&Bs[kk][tx*8];
      *(float4*)&bb[4] = *(const float4*)&Bs[kk][tx*8+4];
#pragma unroll
      for (int i=0;i<8;i++)
#pragma unroll
        for (int j=0;j<8;j++)
          acc[i][j] = fmaf(a[i], bb[j], acc[i][j]);
    }
    __syncthreads();
  }
  float bb1[8];
#pragma unroll
  for (int j=0;j<8;j++){
    int n = n0 + tx*8 + j;
    bb1[j] = b1z[n] + (b2z ? b2z[n] : 0.f);
  }
#pragma unroll
  for (int i=0;i<8;i++){
    int m = m0 + ty*8 + i;
    float o[8];
#pragma unroll
    for (int j=0;j<8;j++) o[j] = acc[i][j] + bb1[j];
    *(float4*)(Cz + (size_t)m*ldc + n0 + tx*8)     = *(const float4*)&o[0];
    *(float4*)(Cz + (size_t)m*ldc + n0 + tx*8 + 4) = *(const float4*)&o[4];
  }
}

// ---------------- dec2: recurrent, block = (dir, batch), 16 waves ----------------
__global__ __launch_bounds__(1024) void k_rec2(
    const float* __restrict__ xg,   // [2][64][60][1024]
    const uint4* __restrict__ wT,   // [2][32][1024] bf16x8
    float* __restrict__ out)        // [64][60][512]
{
  int b = blockIdx.x, d = blockIdx.y, tid = threadIdx.x;
  __shared__ __align__(16) float hls[256];
  __shared__ float gls[1024];
  float c = 0.f;
  if (tid < 256) hls[tid] = 0.f;
  __syncthreads();
  const uint4* wp = wT + (size_t)d*32*1024;
  const float* xp = xg + (((size_t)d*64 + b)*60)*1024;
  for (int step=0; step<TDEC; step++){
    int t = d ? (TDEC-1-step) : step;
    float g = xp[(size_t)t*1024 + tid];
#pragma unroll 4
    for (int j8=0;j8<32;j8++){
      uint4 wv = wp[j8*1024 + tid];
      float4 h0 = *(const float4*)&hls[j8*8];
      float4 h1 = *(const float4*)&hls[j8*8+4];
      GATE8(g, wv, h0, h1)
    }
    gls[tid] = g;
    __syncthreads();
    if (tid < 256){
      float ii = sigf(gls[tid]);
      float ff = sigf(gls[256+tid]);
      float gg = tanhf(gls[512+tid]);
      float oo = sigf(gls[768+tid]);
      c = fmaf(ff, c, ii*gg);
      float hn = oo * tanhf(c);
      hls[tid] = hn;
      out[((size_t)b*60 + t)*512 + d*256 + tid] = hn;
    }
    __syncthreads();
  }
}

extern "C" void kernel_launch(void* const* d_in, const int* in_sizes, int n_in,
                              void* d_out, int out_size, void* d_ws, size_t ws_size,
                              hipStream_t stream) {
  const float* x      = (const float*)d_in[0];
  const float* cw1    = (const float*)d_in[1];
  const float* cb1    = (const float*)d_in[2];
  const float* cw2    = (const float*)d_in[3];
  const float* cb2    = (const float*)d_in[4];
  const float* cw3    = (const float*)d_in[5];
  const float* cb3    = (const float*)d_in[6];
  const float* attn_w = (const float*)d_in[7];
  // d_in[8] attn_b: constant over softmax axis -> drops out analytically
  const float* d1_wih = (const float*)d_in[9];
  const float* d1_whh = (const float*)d_in[10];
  const float* d1_bih = (const float*)d_in[11];
  const float* d1_bhh = (const float*)d_in[12];
  const float* w2_ih0 = (const float*)d_in[13];
  const float* w2_hh0 = (const float*)d_in[14];
  const float* b2_ih0 = (const float*)d_in[15];
  const float* b2_hh0 = (const float*)d_in[16];
  const float* w2_ih1 = (const float*)d_in[17];
  const float* w2_hh1 = (const float*)d_in[18];
  const float* b2_ih1 = (const float*)d_in[19];
  const float* b2_hh1 = (const float*)d_in[20];
  const float* out_w  = (const float*)d_in[21];
  const float* out_b  = (const float*)d_in[22];

  char* ws = (char*)d_ws;
  size_t off = 0;
  // enc region: u8 enc (8.34 MB) + rowscales (1.04 MB)
  uint4* encq = (uint4*)(ws + off);                                // [B][L3C][2] uint4
  float* encs = (float*)(ws + off + 8338432);                      // [B][L3C]
  off += 16675840;
  size_t off_h1 = off;
  float* h1buf = (float*)(ws + off); off += 8382464;               // (B,4093,8)
  float* h2buf = (float*)(ws + off); off += 16736256;              // (B,4086,16)
  float* d2in  = (float*)(ws + off_h1);                            // reuse: (B,60,512)
  float* l0    = (float*)(ws + off_h1 + 7864320);
  float* l1    = (float*)(ws + off_h1 + 15728640);
  uint4* wT    = (uint4*)(ws + off_h1 + 23592960);                 // 1MB dec2 pack (dead tail)
  float* xg    = (float*)(ws + off); off += 31457280;              // [2][B][60][1024]
  // dec1 packs live INSIDE the xg region (xg written only after dec1 completes)
  uint4* d1whhT = (uint4*)xg;                                      // 1 MB
  uint4* d1wihT = (uint4*)((char*)xg + 1048576);                   // +128 KB
  (void)ws_size; (void)in_sizes; (void)n_in; (void)out_size;

  // dec1 weight packs (before dec1; clobbered later by xg — fine)
  k_packw2<<<256,256,0,stream>>>(d1_whh, d1whhT, 256);
  k_packw2<<<32, 256,0,stream>>>(d1_wih, d1wihT, 32);

  int g1 = (B_*L1C + 255)/256;
  k_conv<64,8,4><<<g1,256,0,stream>>>(x, cw1, cb1, h1buf, 4096, L1C);
  int g2 = (B_*L2C + 255)/256;
  k_conv<8,16,8><<<g2,256,0,stream>>>(h1buf, cw2, cb2, h2buf, L1C, L2C);
  int g3 = (B_*L3C + 255)/256;
  k_conv3q<<<g3,256,0,stream>>>(h2buf, cw3, cb3, encq, encs, L2C, L3C);

  // dec1: 128 independent blocks (b,d); enc u8 in LDS; quad split; static-bound softmax
  k_dec1g<<<dim3(64,2),1024,0,stream>>>(encq, encs, attn_w, d1wihT, d1whhT,
                                        d1_bih, d1_bhh, d2in);

  // dec2 layer 0
  k_packw2<<<256,256,0,stream>>>(w2_hh0, wT, 256);
  k_gemm<<<dim3(30,8,2),256,0,stream>>>(d2in, w2_ih0, xg, b2_ih0, b2_hh0,
                                        512, 1024, (size_t)1024*512, (size_t)3840*1024, 1024);
  k_rec2<<<dim3(64,2),1024,0,stream>>>(xg, wT, l0);
  // dec2 layer 1
  k_packw2<<<256,256,0,stream>>>(w2_hh1, wT, 256);
  k_gemm<<<dim3(30,8,2),256,0,stream>>>(l0, w2_ih1, xg, b2_ih1, b2_hh1,
                                        512, 1024, (size_t)1024*512, (size_t)3840*1024, 1024);
  k_rec2<<<dim3(64,2),1024,0,stream>>>(xg, wT, l1);
  // output projection
  k_gemm<<<dim3(30,1,1),256,0,stream>>>(l1, out_w, (float*)d_out, out_b, nullptr,
                                        512, 128, 0, 0, 0);
}